// Round 2
// baseline (471.475 us; speedup 1.0000x reference)
//
#include <hip/hip_runtime.h>
#include <hip/hip_bf16.h>

#define B_ 8
#define H_ 8
#define S_ 1024
#define D_ 64

typedef __attribute__((ext_vector_type(8))) short bf16x8;
typedef __attribute__((ext_vector_type(4))) short bf16x4;
typedef __attribute__((ext_vector_type(4))) float f32x4;

__device__ __forceinline__ short f2bf(float f) {
  union { float f; unsigned u; } x; x.f = f;
  unsigned r = (x.u + 0x7FFFu + ((x.u >> 16) & 1u)) >> 16;
  return (short)r;
}

// ---------------- pre-pass 1: Q and K f32 -> bf16 in one launch ----------------
__global__ __launch_bounds__(256) void cvt_qk(const float* __restrict__ Q,
                                              const float* __restrict__ K,
                                              short* __restrict__ Qb,
                                              short* __restrict__ Kb) {
  const float* in = blockIdx.y ? K : Q;
  short* out      = blockIdx.y ? Kb : Qb;
  const size_t i = ((size_t)blockIdx.x * 256 + threadIdx.x) * 8;
  float4 a = *(const float4*)(in + i);
  float4 b = *(const float4*)(in + i + 4);
  bf16x8 f;
  f[0] = f2bf(a.x); f[1] = f2bf(a.y); f[2] = f2bf(a.z); f[3] = f2bf(a.w);
  f[4] = f2bf(b.x); f[5] = f2bf(b.y); f[6] = f2bf(b.z); f[7] = f2bf(b.w);
  *(bf16x8*)(out + i) = f;
}

// ------------- pre-pass 2: V[bh][s][d] f32 -> Vt[bh][d][s] bf16 -------------
__global__ __launch_bounds__(256) void vtrans(const float* __restrict__ V,
                                              short* __restrict__ Vt) {
  const int bh = blockIdx.y;
  const int s0 = blockIdx.x * 64;
  __shared__ float tile[64][65];
  const float* Vb = V + ((size_t)bh * S_ + s0) * D_;
  const int t = threadIdx.x;
  {
    const int rbase = t >> 4;
    const int c4 = (t & 15) * 4;
    #pragma unroll
    for (int i = 0; i < 4; ++i) {
      const int row = i * 16 + rbase;
      float4 v = *(const float4*)(Vb + (size_t)row * D_ + c4);
      tile[row][c4 + 0] = v.x; tile[row][c4 + 1] = v.y;
      tile[row][c4 + 2] = v.z; tile[row][c4 + 3] = v.w;
    }
  }
  __syncthreads();
  const int d = t >> 2;
  const int sq = (t & 3) * 16;
  short* op = Vt + ((size_t)bh * D_ + d) * S_ + s0 + sq;
  bf16x8 a, b;
  #pragma unroll
  for (int j = 0; j < 8; ++j) {
    a[j] = f2bf(tile[sq + j][d]);
    b[j] = f2bf(tile[sq + 8 + j][d]);
  }
  *(bf16x8*)op = a;
  *(bf16x8*)(op + 8) = b;
}

// ------------------------------ main kernel --------------------------------
// Swapped-operand scores: lane holds q = lane&15 (fixed), k = kt*16+quad*4+r.
// Register-pipelined K and Vt loads (3 deep), 2 barriers total,
// per-wave partial softmax with rescale merged at one barrier.
constexpr int QT  = 16;             // q rows per workgroup
constexpr int NW  = 4;              // waves per workgroup
constexpr int TPW = (S_ / 16) / NW; // 16 k-tiles per wave

__global__ __launch_bounds__(256, 4) void attn_fused(
    const short* __restrict__ Qb16, const short* __restrict__ Kb16,
    const short* __restrict__ Vt,
    float* __restrict__ O, float* __restrict__ A)
{
  // XCD-aware swizzle: 4096 blocks, 4096 % 8 == 0 -> bijective.
  const int nwg = (S_ / QT) * B_ * H_;     // 4096
  const int cpx = nwg / 8;                 // 512
  const int lin = blockIdx.x;
  const int swz = (lin & 7) * cpx + (lin >> 3);
  const int bh  = swz / (S_ / QT);
  const int q0  = (swz % (S_ / QT)) * QT;

  const int tid  = threadIdx.x;
  const int wave = tid >> 6;
  const int lane = tid & 63;
  const int m    = lane & 15;
  const int quad = lane >> 4;

  const short* Qb  = Qb16 + (size_t)bh * S_ * D_;
  const short* Kb  = Kb16 + (size_t)bh * S_ * D_;
  const short* Vtb = Vt   + (size_t)bh * D_ * S_;
  float* Ob = O + (size_t)bh * S_ * D_;
  float* Ab = A + (size_t)bh * S_ * S_;

  __shared__ float redmax[NW][QT];
  __shared__ float redsum[NW][QT];
  __shared__ float obuf[NW][QT][D_ + 4];

  // Q fragment (B-operand): lane holds Q[q0+m][quad*8+j]
  bf16x8 qf0, qf1;
  {
    const short* qp = Qb + (size_t)(q0 + m) * D_ + quad * 8;
    qf0 = *(const bf16x8*)qp;
    qf1 = *(const bf16x8*)(qp + 32);
  }

  // ---- scores, 3-deep register pipeline on K tiles ----
  const short* kbase = Kb + (size_t)m * D_ + quad * 8;
  f32x4 acc[TPW];
  bf16x8 ka0[4], ka1[4];
  #pragma unroll
  for (int p = 0; p < 3; ++p) {
    const short* kp = kbase + (size_t)((p * NW + wave) * 16) * D_;
    ka0[p] = *(const bf16x8*)kp;
    ka1[p] = *(const bf16x8*)(kp + 32);
  }
  #pragma unroll
  for (int t = 0; t < TPW; ++t) {
    if (t + 3 < TPW) {
      const short* kp = kbase + (size_t)(((t + 3) * NW + wave) * 16) * D_;
      ka0[(t + 3) & 3] = *(const bf16x8*)kp;
      ka1[(t + 3) & 3] = *(const bf16x8*)(kp + 32);
    }
    f32x4 c = {0.f, 0.f, 0.f, 0.f};
    c = __builtin_amdgcn_mfma_f32_16x16x32_bf16(ka0[t & 3], qf0, c, 0, 0, 0);
    c = __builtin_amdgcn_mfma_f32_16x16x32_bf16(ka1[t & 3], qf1, c, 0, 0, 0);
    acc[t] = c;
  }

  // ---- wave-local column max (tree), then exp immediately ----
  float mx[TPW];
  #pragma unroll
  for (int t = 0; t < TPW; ++t)
    mx[t] = fmaxf(fmaxf(acc[t][0], acc[t][1]), fmaxf(acc[t][2], acc[t][3]));
  #pragma unroll
  for (int sstep = TPW / 2; sstep > 0; sstep >>= 1) {
    #pragma unroll
    for (int t = 0; t < sstep; ++t) mx[t] = fmaxf(mx[t], mx[t + sstep]);
  }
  float vmax = mx[0];
  vmax = fmaxf(vmax, __shfl_xor(vmax, 16));
  vmax = fmaxf(vmax, __shfl_xor(vmax, 32));

  constexpr float CE = 0.125f * 1.4426950408889634f;
  float sm[TPW];
  #pragma unroll
  for (int t = 0; t < TPW; ++t) {
    float e0 = __builtin_exp2f((acc[t][0] - vmax) * CE);
    float e1 = __builtin_exp2f((acc[t][1] - vmax) * CE);
    float e2 = __builtin_exp2f((acc[t][2] - vmax) * CE);
    float e3 = __builtin_exp2f((acc[t][3] - vmax) * CE);
    acc[t][0] = e0; acc[t][1] = e1; acc[t][2] = e2; acc[t][3] = e3;
    sm[t] = (e0 + e1) + (e2 + e3);
  }
  #pragma unroll
  for (int sstep = TPW / 2; sstep > 0; sstep >>= 1) {
    #pragma unroll
    for (int t = 0; t < sstep; ++t) sm[t] += sm[t + sstep];
  }
  float psum = sm[0];
  psum += __shfl_xor(psum, 16);
  psum += __shfl_xor(psum, 32);

  if (lane < 16) {
    redmax[wave][lane] = vmax;
    redsum[wave][lane] = psum;
  }
  __syncthreads();

  // ---- merge wave partials: gmax + rescaled sum ----
  float m0 = redmax[0][m], m1 = redmax[1][m], m2 = redmax[2][m], m3 = redmax[3][m];
  const float gmax = fmaxf(fmaxf(m0, m1), fmaxf(m2, m3));
  float sumg = redsum[0][m] * __builtin_exp2f((m0 - gmax) * CE)
             + redsum[1][m] * __builtin_exp2f((m1 - gmax) * CE)
             + redsum[2][m] * __builtin_exp2f((m2 - gmax) * CE)
             + redsum[3][m] * __builtin_exp2f((m3 - gmax) * CE);
  const float rinv = __builtin_exp2f((vmax - gmax) * CE) / sumg;

  // ---- fused: normalize -> A store (NT dwordx4) -> pack -> PV MFMA ----
  // Vt loads pipelined 3 iterations deep.
  const short* vbase = Vtb + (size_t)m * S_ + quad * 4;
  bf16x4 vb[4][4];
  #pragma unroll
  for (int p = 0; p < 3; ++p) {
    const short* vp = vbase + (p * NW + wave) * 16;
    #pragma unroll
    for (int i = 0; i < 4; ++i)
      vb[p][i] = *(const bf16x4*)(vp + (size_t)(16 * i) * S_);
  }

  f32x4 oc0 = {0.f,0.f,0.f,0.f}, oc1 = {0.f,0.f,0.f,0.f};
  f32x4 oc2 = {0.f,0.f,0.f,0.f}, oc3 = {0.f,0.f,0.f,0.f};
  float* arow = Ab + (size_t)(q0 + m) * S_ + quad * 4;
  #pragma unroll
  for (int t = 0; t < TPW; ++t) {
    if (t + 3 < TPW) {
      const short* vp = vbase + ((t + 3) * NW + wave) * 16;
      #pragma unroll
      for (int i = 0; i < 4; ++i)
        vb[(t + 3) & 3][i] = *(const bf16x4*)(vp + (size_t)(16 * i) * S_);
    }
    const int kt = t * NW + wave;
    f32x4 pn = acc[t] * rinv;
    __builtin_nontemporal_store(pn, (f32x4*)(arow + kt * 16));
    bf16x4 pa;
    pa[0] = f2bf(pn[0]); pa[1] = f2bf(pn[1]);
    pa[2] = f2bf(pn[2]); pa[3] = f2bf(pn[3]);
    oc0 = __builtin_amdgcn_mfma_f32_16x16x16bf16_1k(pa, vb[t & 3][0], oc0, 0, 0, 0);
    oc1 = __builtin_amdgcn_mfma_f32_16x16x16bf16_1k(pa, vb[t & 3][1], oc1, 0, 0, 0);
    oc2 = __builtin_amdgcn_mfma_f32_16x16x16bf16_1k(pa, vb[t & 3][2], oc2, 0, 0, 0);
    oc3 = __builtin_amdgcn_mfma_f32_16x16x16bf16_1k(pa, vb[t & 3][3], oc3, 0, 0, 0);
  }

  // ---- cross-wave O reduction via LDS ----
  #pragma unroll
  for (int r = 0; r < 4; ++r) {
    obuf[wave][quad * 4 + r][m]      = oc0[r];
    obuf[wave][quad * 4 + r][16 + m] = oc1[r];
    obuf[wave][quad * 4 + r][32 + m] = oc2[r];
    obuf[wave][quad * 4 + r][48 + m] = oc3[r];
  }
  __syncthreads();
  {
    const int q  = tid >> 4;          // 0..15
    const int d4 = (tid & 15) * 4;    // 0..60
    f32x4 o0 = *(const f32x4*)&obuf[0][q][d4];
    f32x4 o1 = *(const f32x4*)&obuf[1][q][d4];
    f32x4 o2 = *(const f32x4*)&obuf[2][q][d4];
    f32x4 o3 = *(const f32x4*)&obuf[3][q][d4];
    f32x4 o = (o0 + o1) + (o2 + o3);
    *(f32x4*)&Ob[(size_t)(q0 + q) * D_ + d4] = o;
  }
}

extern "C" void kernel_launch(void* const* d_in, const int* in_sizes, int n_in,
                              void* d_out, int out_size, void* d_ws, size_t ws_size,
                              hipStream_t stream) {
  const float* Q = (const float*)d_in[0];
  const float* K = (const float*)d_in[1];
  const float* V = (const float*)d_in[2];
  float* O = (float*)d_out;
  float* A = O + (size_t)B_ * H_ * S_ * D_;

  const size_t NEL = (size_t)B_ * H_ * S_ * D_;  // 4194304
  short* Qbf = (short*)d_ws;
  short* Kbf = Qbf + NEL;
  short* Vtb = Kbf + NEL;

  const int cvt_blocks = (int)(NEL / 8 / 256);   // 2048
  cvt_qk<<<dim3(cvt_blocks, 2), 256, 0, stream>>>(Q, K, Qbf, Kbf);
  vtrans<<<dim3(S_ / 64, B_ * H_), 256, 0, stream>>>(V, Vtb);

  attn_fused<<<(S_ / QT) * B_ * H_, NW * 64, 0, stream>>>(Qbf, Kbf, Vtb, O, A);
}

// Round 3
// 459.274 us; speedup vs baseline: 1.0266x; 1.0266x over previous
//
#include <hip/hip_runtime.h>
#include <hip/hip_bf16.h>

#define B_ 8
#define H_ 8
#define S_ 1024
#define D_ 64

typedef __attribute__((ext_vector_type(8))) short bf16x8;
typedef __attribute__((ext_vector_type(4))) short bf16x4;
typedef __attribute__((ext_vector_type(4))) float f32x4;

__device__ __forceinline__ short f2bf(float f) {
  union { float f; unsigned u; } x; x.f = f;
  unsigned r = (x.u + 0x7FFFu + ((x.u >> 16) & 1u)) >> 16;
  return (short)r;
}

// ---------------- pre-pass 1: Q and K f32 -> bf16 in one launch ----------------
__global__ __launch_bounds__(256) void cvt_qk(const float* __restrict__ Q,
                                              const float* __restrict__ K,
                                              short* __restrict__ Qb,
                                              short* __restrict__ Kb) {
  const float* in = blockIdx.y ? K : Q;
  short* out      = blockIdx.y ? Kb : Qb;
  const size_t i = ((size_t)blockIdx.x * 256 + threadIdx.x) * 8;
  float4 a = *(const float4*)(in + i);
  float4 b = *(const float4*)(in + i + 4);
  bf16x8 f;
  f[0] = f2bf(a.x); f[1] = f2bf(a.y); f[2] = f2bf(a.z); f[3] = f2bf(a.w);
  f[4] = f2bf(b.x); f[5] = f2bf(b.y); f[6] = f2bf(b.z); f[7] = f2bf(b.w);
  *(bf16x8*)(out + i) = f;
}

// ------------- pre-pass 2: V[bh][s][d] f32 -> Vt[bh][d][s] bf16 -------------
__global__ __launch_bounds__(256) void vtrans(const float* __restrict__ V,
                                              short* __restrict__ Vt) {
  const int bh = blockIdx.y;
  const int s0 = blockIdx.x * 64;
  __shared__ float tile[64][65];
  const float* Vb = V + ((size_t)bh * S_ + s0) * D_;
  const int t = threadIdx.x;
  {
    const int rbase = t >> 4;
    const int c4 = (t & 15) * 4;
    #pragma unroll
    for (int i = 0; i < 4; ++i) {
      const int row = i * 16 + rbase;
      float4 v = *(const float4*)(Vb + (size_t)row * D_ + c4);
      tile[row][c4 + 0] = v.x; tile[row][c4 + 1] = v.y;
      tile[row][c4 + 2] = v.z; tile[row][c4 + 3] = v.w;
    }
  }
  __syncthreads();
  const int d = t >> 2;
  const int sq = (t & 3) * 16;
  short* op = Vt + ((size_t)bh * D_ + d) * S_ + s0 + sq;
  bf16x8 a, b;
  #pragma unroll
  for (int j = 0; j < 8; ++j) {
    a[j] = f2bf(tile[sq + j][d]);
    b[j] = f2bf(tile[sq + 8 + j][d]);
  }
  *(bf16x8*)op = a;
  *(bf16x8*)(op + 8) = b;
}

// ------------------------------ main kernel --------------------------------
// Swapped-operand scores: lane holds q = lane&15 (fixed), k = kt*16+quad*4+r.
// k-ownership: kt(t) = (t>>2)*16 + wave*4 + (t&3), so per group g the 4 waves
// tile a CONTIGUOUS 256-col band [g*256, g*256+256). A-tile is staged in LDS
// (double-buffered) and stored as 1KB-contiguous dwordx4 wave-instructions.
constexpr int QT  = 16;             // q rows per workgroup
constexpr int NW  = 4;              // waves per workgroup
constexpr int TPW = (S_ / 16) / NW; // 16 k-tiles per wave
constexpr int CH_STRIDE = 260;      // chunk row stride (words), 16B-aligned

__global__ __launch_bounds__(256, 4) void attn_fused(
    const short* __restrict__ Qb16, const short* __restrict__ Kb16,
    const short* __restrict__ Vt,
    float* __restrict__ O, float* __restrict__ A)
{
  // XCD-aware swizzle: 4096 blocks, 4096 % 8 == 0 -> bijective.
  const int nwg = (S_ / QT) * B_ * H_;     // 4096
  const int cpx = nwg / 8;                 // 512
  const int lin = blockIdx.x;
  const int swz = (lin & 7) * cpx + (lin >> 3);
  const int bh  = swz / (S_ / QT);
  const int q0  = (swz % (S_ / QT)) * QT;

  const int tid  = threadIdx.x;
  const int wave = tid >> 6;
  const int lane = tid & 63;
  const int m    = lane & 15;
  const int quad = lane >> 4;

  const short* Qb  = Qb16 + (size_t)bh * S_ * D_;
  const short* Kb  = Kb16 + (size_t)bh * S_ * D_;
  const short* Vtb = Vt   + (size_t)bh * D_ * S_;
  float* Ob = O + (size_t)bh * S_ * D_;
  float* Ab = A + (size_t)bh * S_ * S_;

  // smem: chunk[2][16][260] f32 (33280 B), overlaid by obuf[4][16][68] at end.
  __shared__ float smem[2 * 16 * CH_STRIDE];
  __shared__ float redmax[NW][QT];
  __shared__ float redsum[NW][QT];

  // Q fragment (B-operand): lane holds Q[q0+m][quad*8+j]
  bf16x8 qf0, qf1;
  {
    const short* qp = Qb + (size_t)(q0 + m) * D_ + quad * 8;
    qf0 = *(const bf16x8*)qp;
    qf1 = *(const bf16x8*)(qp + 32);
  }

  // ---- scores: kt(t) = (t>>2)*16 + wave*4 + (t&3) ----
  const short* kbase = Kb + (size_t)m * D_ + quad * 8;
  f32x4 acc[TPW];
  bf16x8 ka0[4], ka1[4];
  #pragma unroll
  for (int p = 0; p < 3; ++p) {
    const int row = wave * 64 + p * 16;   // (p>>2)==0 for p<3
    const short* kp = kbase + (size_t)row * D_;
    ka0[p] = *(const bf16x8*)kp;
    ka1[p] = *(const bf16x8*)(kp + 32);
  }
  #pragma unroll
  for (int t = 0; t < TPW; ++t) {
    if (t + 3 < TPW) {
      const int tn = t + 3;
      const int row = (tn >> 2) * 256 + wave * 64 + (tn & 3) * 16;
      const short* kp = kbase + (size_t)row * D_;
      ka0[tn & 3] = *(const bf16x8*)kp;
      ka1[tn & 3] = *(const bf16x8*)(kp + 32);
    }
    f32x4 c = {0.f, 0.f, 0.f, 0.f};
    c = __builtin_amdgcn_mfma_f32_16x16x32_bf16(ka0[t & 3], qf0, c, 0, 0, 0);
    c = __builtin_amdgcn_mfma_f32_16x16x32_bf16(ka1[t & 3], qf1, c, 0, 0, 0);
    acc[t] = c;
  }

  // ---- wave-local column max (tree), then exp immediately ----
  float mx[TPW];
  #pragma unroll
  for (int t = 0; t < TPW; ++t)
    mx[t] = fmaxf(fmaxf(acc[t][0], acc[t][1]), fmaxf(acc[t][2], acc[t][3]));
  #pragma unroll
  for (int sstep = TPW / 2; sstep > 0; sstep >>= 1) {
    #pragma unroll
    for (int t = 0; t < sstep; ++t) mx[t] = fmaxf(mx[t], mx[t + sstep]);
  }
  float vmax = mx[0];
  vmax = fmaxf(vmax, __shfl_xor(vmax, 16));
  vmax = fmaxf(vmax, __shfl_xor(vmax, 32));

  constexpr float CE = 0.125f * 1.4426950408889634f;
  float sm[TPW];
  #pragma unroll
  for (int t = 0; t < TPW; ++t) {
    float e0 = __builtin_exp2f((acc[t][0] - vmax) * CE);
    float e1 = __builtin_exp2f((acc[t][1] - vmax) * CE);
    float e2 = __builtin_exp2f((acc[t][2] - vmax) * CE);
    float e3 = __builtin_exp2f((acc[t][3] - vmax) * CE);
    acc[t][0] = e0; acc[t][1] = e1; acc[t][2] = e2; acc[t][3] = e3;
    sm[t] = (e0 + e1) + (e2 + e3);
  }
  #pragma unroll
  for (int sstep = TPW / 2; sstep > 0; sstep >>= 1) {
    #pragma unroll
    for (int t = 0; t < sstep; ++t) sm[t] += sm[t + sstep];
  }
  float psum = sm[0];
  psum += __shfl_xor(psum, 16);
  psum += __shfl_xor(psum, 32);

  if (lane < 16) {
    redmax[wave][lane] = vmax;
    redsum[wave][lane] = psum;
  }
  __syncthreads();

  // ---- merge wave partials: gmax + rescaled sum ----
  float m0 = redmax[0][m], m1 = redmax[1][m], m2 = redmax[2][m], m3 = redmax[3][m];
  const float gmax = fmaxf(fmaxf(m0, m1), fmaxf(m2, m3));
  float sumg = redsum[0][m] * __builtin_exp2f((m0 - gmax) * CE)
             + redsum[1][m] * __builtin_exp2f((m1 - gmax) * CE)
             + redsum[2][m] * __builtin_exp2f((m2 - gmax) * CE)
             + redsum[3][m] * __builtin_exp2f((m3 - gmax) * CE);
  const float rinv = __builtin_exp2f((vmax - gmax) * CE) / sumg;

  // ---- PV + A-store in 4 groups of 256 contiguous columns ----
  const short* vbase = Vtb + (size_t)m * S_ + quad * 4;
  f32x4 oc0 = {0.f,0.f,0.f,0.f}, oc1 = {0.f,0.f,0.f,0.f};
  f32x4 oc2 = {0.f,0.f,0.f,0.f}, oc3 = {0.f,0.f,0.f,0.f};

  #pragma unroll
  for (int g = 0; g < 4; ++g) {
    float* chunk = smem + (g & 1) * (16 * CH_STRIDE);
    #pragma unroll
    for (int c = 0; c < 4; ++c) {
      const int t = g * 4 + c;
      const int kcol = g * 256 + wave * 64 + c * 16;  // global k base of tile
      f32x4 pn = acc[t] * rinv;
      *(f32x4*)&chunk[m * CH_STRIDE + wave * 64 + c * 16 + quad * 4] = pn;
      bf16x4 pa;
      pa[0] = f2bf(pn[0]); pa[1] = f2bf(pn[1]);
      pa[2] = f2bf(pn[2]); pa[3] = f2bf(pn[3]);
      const short* vp = vbase + kcol;
      bf16x4 bv0 = *(const bf16x4*)(vp);
      bf16x4 bv1 = *(const bf16x4*)(vp + (size_t)16 * S_);
      bf16x4 bv2 = *(const bf16x4*)(vp + (size_t)32 * S_);
      bf16x4 bv3 = *(const bf16x4*)(vp + (size_t)48 * S_);
      oc0 = __builtin_amdgcn_mfma_f32_16x16x16bf16_1k(pa, bv0, oc0, 0, 0, 0);
      oc1 = __builtin_amdgcn_mfma_f32_16x16x16bf16_1k(pa, bv1, oc1, 0, 0, 0);
      oc2 = __builtin_amdgcn_mfma_f32_16x16x16bf16_1k(pa, bv2, oc2, 0, 0, 0);
      oc3 = __builtin_amdgcn_mfma_f32_16x16x16bf16_1k(pa, bv3, oc3, 0, 0, 0);
    }
    __syncthreads();
    // store the 16x256 band: each wave-instruction = 1KB contiguous
    #pragma unroll
    for (int rep = 0; rep < 4; ++rep) {
      const int row = rep * 4 + wave;
      const f32x4 v = *(const f32x4*)&chunk[row * CH_STRIDE + lane * 4];
      *(f32x4*)&Ab[(size_t)(q0 + row) * S_ + g * 256 + lane * 4] = v;
    }
  }
  __syncthreads();   // chunk reads done everywhere before obuf overlays smem

  // ---- cross-wave O reduction via LDS (obuf overlays smem) ----
  {
    float* obuf = smem;                   // [NW][QT][68]
    #pragma unroll
    for (int r = 0; r < 4; ++r) {
      float* orow = obuf + (wave * QT + quad * 4 + r) * 68;
      orow[m]      = oc0[r];
      orow[16 + m] = oc1[r];
      orow[32 + m] = oc2[r];
      orow[48 + m] = oc3[r];
    }
    __syncthreads();
    const int q  = tid >> 4;          // 0..15
    const int d4 = (tid & 15) * 4;    // 0..60
    f32x4 o0 = *(const f32x4*)&obuf[(0 * QT + q) * 68 + d4];
    f32x4 o1 = *(const f32x4*)&obuf[(1 * QT + q) * 68 + d4];
    f32x4 o2 = *(const f32x4*)&obuf[(2 * QT + q) * 68 + d4];
    f32x4 o3 = *(const f32x4*)&obuf[(3 * QT + q) * 68 + d4];
    f32x4 o = (o0 + o1) + (o2 + o3);
    *(f32x4*)&Ob[(size_t)(q0 + q) * D_ + d4] = o;
  }
}

extern "C" void kernel_launch(void* const* d_in, const int* in_sizes, int n_in,
                              void* d_out, int out_size, void* d_ws, size_t ws_size,
                              hipStream_t stream) {
  const float* Q = (const float*)d_in[0];
  const float* K = (const float*)d_in[1];
  const float* V = (const float*)d_in[2];
  float* O = (float*)d_out;
  float* A = O + (size_t)B_ * H_ * S_ * D_;

  const size_t NEL = (size_t)B_ * H_ * S_ * D_;  // 4194304
  short* Qbf = (short*)d_ws;
  short* Kbf = Qbf + NEL;
  short* Vtb = Kbf + NEL;

  const int cvt_blocks = (int)(NEL / 8 / 256);   // 2048
  cvt_qk<<<dim3(cvt_blocks, 2), 256, 0, stream>>>(Q, K, Qbf, Kbf);
  vtrans<<<dim3(S_ / 64, B_ * H_), 256, 0, stream>>>(V, Vtb);

  attn_fused<<<(S_ / QT) * B_ * H_, NW * 64, 0, stream>>>(Qbf, Kbf, Vtb, O, A);
}